// Round 6
// baseline (675.144 us; speedup 1.0000x reference)
//
#include <hip/hip_runtime.h>

// IndexNSW: batched greedy best-first NSW search. One WAVE per query
// (B=64 blocks x 64 threads), zero barriers (single-wave lockstep; DS ops
// are program-ordered within a wave).
//
// R6 = R5 with the butterfly FIXED. R5 shuffled the KEPT element (`mine`),
// so lane l received the partner's partial of the OTHER row (absmax=N fail).
// Correct exchange: keep w[2i+lb], shuffle w[2i+(1-lb)] -- the partner
// (lb'=1-lb) then sends w[2i+lb], the same row we kept.
// Gather is coalesced whole-wave-per-row: instruction j loads row nbid_j,
// lane l takes float4 at byte 16l -> 1KB contiguous per instruction (vs
// R4's 64 divergent addresses/instr = ~2048 serial L1 transactions/step).
// After the 5-stage transpose-reduce + shfl_xor(32), every lane holds the
// full 256-dim distance of row (l&31). Query = 4 regs/lane (its own dims).
// Merge key = (f32 bits of d)<<6 | concat idx: d>=0 so u64 order ==
// (d, idx) lexicographic == lax.top_k stable order (ties incl. dup ids).

#define DIMS   256
#define RDEG   32
#define EFPOOL 32
#define KOUT   10
#define NWORDS 3125     // ceil(100000 / 32)
#define INF_D  1e30f

__global__ __launch_bounds__(64, 1) void nsw_wave_kernel(
    const float* __restrict__ query,    // [B, 256]
    const float* __restrict__ storage,  // [N, 256]
    const int*   __restrict__ graph,    // [N, 32]
    const int*   __restrict__ initial,  // [B, 32]
    float*       __restrict__ out,      // [B*10 ids as float][B*10 dists]
    int B)
{
    __shared__ unsigned int visited[NWORDS];
    __shared__ unsigned int expanded[NWORDS];
    __shared__ unsigned long long keys[64];     // merge keys
    __shared__ float sc_d[EFPOOL];              // merge scatter scratch
    __shared__ int   sc_id[EFPOOL];

    const int l    = threadIdx.x;   // 0..63
    const int b    = blockIdx.x;
    const int nb   = l & 31;        // pool slot / row owned (dup across halves)
    const int half = l >> 5;

    for (int i = l; i < NWORDS; i += 64) { visited[i] = 0u; expanded[i] = 0u; }

    // lane's 4 query dims [4l, 4l+4) in registers
    const float4 q = reinterpret_cast<const float4*>(query + (size_t)b * DIMS)[l];

    float pool_d  = INF_D;   // dummy pool; first merge sorts the real entries in
    int   pool_id = 0;
    int   u = 0;             // next node to expand (set by merge_pick)

    // Coalesced gather + transpose-reduce: given per-lane nbid (lane j<32
    // holds id for row j; halves duplicate), return D(row l&31) in every lane.
    auto dist32 = [&](int nbid) -> float {
        float4 r[32];
        #pragma unroll
        for (int j = 0; j < 32; ++j) {          // row j whole-wave: lane l -> bytes [16l,16l+16)
            int idj = __shfl(nbid, j, 64);      // row id, broadcast from lane j
            r[j] = reinterpret_cast<const float4*>(storage + (size_t)idj * DIMS)[l];
        }
        float w[32];
        #pragma unroll
        for (int j = 0; j < 32; ++j) {          // per-lane 4-dim partial of row j
            float d0 = r[j].x - q.x; float a = d0 * d0;
            float d1 = r[j].y - q.y; a = fmaf(d1, d1, a);
            float d2 = r[j].z - q.z; a = fmaf(d2, d2, a);
            float d3 = r[j].w - q.w; a = fmaf(d3, d3, a);
            w[j] = a;
        }
        // transpose-reduce: keep w[2i+lb], SHUFFLE w[2i+(1-lb)] (partner
        // sends the row we kept). After stage k, w[i](l) = partial of row
        // i*2^(k+1) + (l mod 2^(k+1)) over lanes agreeing on bits k+1..5.
        #pragma unroll
        for (int k = 0; k < 5; ++k) {
            const int m  = 1 << k;
            const int lb = (l >> k) & 1;
            #pragma unroll
            for (int i = 0; i < (16 >> k); ++i) {
                float mine  = w[2 * i + lb];
                float other = w[2 * i + (1 - lb)];
                w[i] = mine + __shfl_xor(other, m, 64);
            }
        }
        return w[0] + __shfl_xor(w[0], 32, 64); // D(row l&31), all lanes
    };

    // merge 64 concat elements (lane l owns concat idx l: [0,32)=old pool,
    // [32,64)=new cands) == lax.top_k(-all_d, 32); then pick next u = first
    // unexpanded slot of the sorted pool (== reference argmin).
    auto merge_pick = [&](float nd, int nbid) {
        float ed  = half ? nd   : pool_d;
        int   eid = half ? nbid : pool_id;
        unsigned long long key =
            ((unsigned long long)__float_as_uint(ed) << 6) | (unsigned)l;
        keys[l] = key;
        int rank = 0;
        #pragma unroll
        for (int j = 0; j < 64; ++j)            // same addr all lanes: broadcast
            rank += (keys[j] < key) ? 1 : 0;
        if (rank < EFPOOL) { sc_d[rank] = ed; sc_id[rank] = eid; }  // ranks unique
        pool_d  = sc_d[nb];                     // in-order DS: no barrier
        pool_id = sc_id[nb];
        bool unexp = !((expanded[pool_id >> 5] >> (pool_id & 31)) & 1u);
        unsigned long long m = __ballot(unexp && (l < 32));
        int slot = (m == 0ull) ? 0 : (__ffsll(m) - 1);
        u = __builtin_amdgcn_readfirstlane(sc_id[slot]);
        if (l == 0) expanded[u >> 5] |= (1u << (u & 31));   // sole writer
    };

    // ---- initial pool: dists of init ids, merged vs dummy INF pool ----
    {
        int nbid = initial[b * EFPOOL + nb];    // halves duplicate
        if (l < 32) atomicOr(&visited[nbid >> 5], 1u << (nbid & 31));
        float nd = dist32(nbid);
        merge_pick(nd, nbid);
    }

    // ---- ef_search expansion steps ----
    for (int step = 0; step < EFPOOL; ++step) {
        // neighbor ids: coalesced 128B row (halves duplicate)
        int nbid = graph[(size_t)u * RDEG + nb];

        float d = dist32(nbid);                 // gathers issue before visited check

        // fresh = !visited pre-update (reads precede ORs: program order)
        unsigned vw = visited[nbid >> 5];
        bool fresh = !((vw >> (nbid & 31)) & 1u);
        if ((l < 32) && fresh) atomicOr(&visited[nbid >> 5], 1u << (nbid & 31));

        float nd = fresh ? d : INF_D;
        merge_pick(nd, nbid);
    }

    // ---- output: pool sorted ascending; ids as float (exact < 2^24), then dists ----
    if (l < KOUT) {
        out[b * KOUT + l]            = (float)pool_id;
        out[B * KOUT + b * KOUT + l] = pool_d;
    }
}

extern "C" void kernel_launch(void* const* d_in, const int* in_sizes, int n_in,
                              void* d_out, int out_size, void* d_ws, size_t ws_size,
                              hipStream_t stream) {
    const float* query   = (const float*)d_in[0];
    const float* storage = (const float*)d_in[1];
    const int*   graph   = (const int*)d_in[2];
    const int*   initial = (const int*)d_in[3];
    float* out = (float*)d_out;

    const int B = in_sizes[0] / DIMS;   // 64

    nsw_wave_kernel<<<B, 64, 0, stream>>>(query, storage, graph, initial, out, B);
}